// Round 7
// baseline (52.718 us; speedup 1.0000x reference)
//
#include <hip/hip_runtime.h>
#include <math.h>

#define HDIM 2048
#define NEXP 8
#define TB 4                          // tokens per wave
#define BLOCK 512
#define WAVES_PB 8
#define TOK_PB (WAVES_PB * TB)        // 32 tokens per block

// ---------------------------------------------------------------------------
// R7: token-major x streaming. All prior rounds interleaved 4 token-streams
// per wave (16K concurrent streams chip-wide, ~4/HBM-bank -> row thrash).
// Now each wave reads contiguous 4KB half-row bursts (8 independent float4
// loads issued together), 2 streams/wave. W staged once per block in LDS
// (64 KB) so the VMEM queue carries only the x stream. acc[32] = 4 tok x 8
// experts/lane; R1-verified shuffle-fold -> top-2 -> softmax; histogram via
// LDS counts + 8 float atomics/block (integer-valued float adds are exact
// -> deterministic).
// ---------------------------------------------------------------------------
__global__ __launch_bounds__(BLOCK, 4) void
router_main(const float* __restrict__ x,
            const float* __restrict__ W,
            float* __restrict__ out_scores,   // [T,2]
            float* __restrict__ out_idx,      // [T,2] as float
            float* __restrict__ hist,         // [8], pre-zeroed
            int T)
{
    __shared__ float wlds[NEXP][HDIM];        // 64 KB
    __shared__ int cnt[NEXP];

    // ---- cooperative W -> LDS stage (coalesced; unroll 4 bounds hoisting) ----
    {
        const float4* __restrict__ Wv = reinterpret_cast<const float4*>(W);
        float4* wl = reinterpret_cast<float4*>(&wlds[0][0]);
#pragma unroll 4
        for (int j = 0; j < (NEXP * HDIM / 4) / BLOCK; ++j)    // 8 iters
            wl[threadIdx.x + j * BLOCK] = Wv[threadIdx.x + j * BLOCK];
    }
    if (threadIdx.x < NEXP) cnt[threadIdx.x] = 0;
    __syncthreads();

    const int lane = threadIdx.x & 63;
    const int wv   = threadIdx.x >> 6;
    const int tok0 = blockIdx.x * TOK_PB + wv * TB;

    float acc[TB * NEXP];
#pragma unroll
    for (int i = 0; i < TB * NEXP; ++i) acc[i] = 0.f;

    // ---- token-pair-major: 2 pairs x 2 half-rows; contiguous 4KB bursts ----
#pragma unroll
    for (int p = 0; p < 2; ++p) {
        int ta = tok0 + 2 * p;     if (ta > T - 1) ta = T - 1;
        int tb = tok0 + 2 * p + 1; if (tb > T - 1) tb = T - 1;
        const float* xa = x + (size_t)ta * HDIM + lane * 4;
        const float* xb = x + (size_t)tb * HDIM + lane * 4;

#pragma unroll
        for (int ph = 0; ph < 2; ++ph) {       // half-row = chunks [4ph,4ph+4)
            // burst-prefetch: 8 independent 1KB wave-loads (4KB/token)
            float4 xva[4], xvb[4];
#pragma unroll
            for (int c = 0; c < 4; ++c) {
                xva[c] = *reinterpret_cast<const float4*>(xa + (4 * ph + c) * 256);
                xvb[c] = *reinterpret_cast<const float4*>(xb + (4 * ph + c) * 256);
            }
            // consume against W from LDS, 4 experts at a time
#pragma unroll
            for (int c = 0; c < 4; ++c) {
                const int h = (4 * ph + c) * 256 + lane * 4;
#pragma unroll
                for (int half = 0; half < 2; ++half) {
                    const int b = half * 4;
                    const float4 w0 = *reinterpret_cast<const float4*>(&wlds[b + 0][h]);
                    const float4 w1 = *reinterpret_cast<const float4*>(&wlds[b + 1][h]);
                    const float4 w2 = *reinterpret_cast<const float4*>(&wlds[b + 2][h]);
                    const float4 w3 = *reinterpret_cast<const float4*>(&wlds[b + 3][h]);

                    const int ia = (2 * p + 0) * NEXP + b;
                    const int ib = (2 * p + 1) * NEXP + b;
                    float a0 = acc[ia + 0], a1 = acc[ia + 1], a2 = acc[ia + 2], a3 = acc[ia + 3];
                    float b0 = acc[ib + 0], b1 = acc[ib + 1], b2 = acc[ib + 2], b3 = acc[ib + 3];

                    a0 = fmaf(xva[c].x, w0.x, a0); a0 = fmaf(xva[c].y, w0.y, a0);
                    a0 = fmaf(xva[c].z, w0.z, a0); a0 = fmaf(xva[c].w, w0.w, a0);
                    a1 = fmaf(xva[c].x, w1.x, a1); a1 = fmaf(xva[c].y, w1.y, a1);
                    a1 = fmaf(xva[c].z, w1.z, a1); a1 = fmaf(xva[c].w, w1.w, a1);
                    a2 = fmaf(xva[c].x, w2.x, a2); a2 = fmaf(xva[c].y, w2.y, a2);
                    a2 = fmaf(xva[c].z, w2.z, a2); a2 = fmaf(xva[c].w, w2.w, a2);
                    a3 = fmaf(xva[c].x, w3.x, a3); a3 = fmaf(xva[c].y, w3.y, a3);
                    a3 = fmaf(xva[c].z, w3.z, a3); a3 = fmaf(xva[c].w, w3.w, a3);

                    b0 = fmaf(xvb[c].x, w0.x, b0); b0 = fmaf(xvb[c].y, w0.y, b0);
                    b0 = fmaf(xvb[c].z, w0.z, b0); b0 = fmaf(xvb[c].w, w0.w, b0);
                    b1 = fmaf(xvb[c].x, w1.x, b1); b1 = fmaf(xvb[c].y, w1.y, b1);
                    b1 = fmaf(xvb[c].z, w1.z, b1); b1 = fmaf(xvb[c].w, w1.w, b1);
                    b2 = fmaf(xvb[c].x, w2.x, b2); b2 = fmaf(xvb[c].y, w2.y, b2);
                    b2 = fmaf(xvb[c].z, w2.z, b2); b2 = fmaf(xvb[c].w, w2.w, b2);
                    b3 = fmaf(xvb[c].x, w3.x, b3); b3 = fmaf(xvb[c].y, w3.y, b3);
                    b3 = fmaf(xvb[c].z, w3.z, b3); b3 = fmaf(xvb[c].w, w3.w, b3);

                    acc[ia + 0] = a0; acc[ia + 1] = a1; acc[ia + 2] = a2; acc[ia + 3] = a3;
                    acc[ib + 0] = b0; acc[ib + 1] = b1; acc[ib + 2] = b2; acc[ib + 3] = b3;
                }
            }
        }
    }

    // ---- reduce 32 partial sums across 64 lanes (R1-verified fold) ----
#pragma unroll
    for (int j = 0; j < 32; ++j) acc[j] += __shfl_xor(acc[j], 32, 64);

#define FOLD(SM)                                                          \
    {                                                                     \
        const bool up = (lane & SM) != 0;                                 \
        _Pragma("unroll")                                                 \
        for (int j = 0; j < SM; ++j) {                                    \
            float keep = up ? acc[j + SM] : acc[j];                       \
            float send = up ? acc[j] : acc[j + SM];                       \
            acc[j] = keep + __shfl_xor(send, SM, 64);                     \
        }                                                                 \
    }
    FOLD(16) FOLD(8) FOLD(4) FOLD(2) FOLD(1)
#undef FOLD

    // lane l holds logit(token tok0 + ((l&31)>>3), expert l&7)
    const int e_my  = lane & 7;
    const int t_loc = (lane & 31) >> 3;
    const float mylg = acc[0];

    // ---- top-1 within each aligned 8-lane group (tie -> lower index) ----
    float v1 = mylg;
    int   i1 = e_my;
#pragma unroll
    for (int m = 1; m <= 4; m <<= 1) {
        float ov = __shfl_xor(v1, m, 64);
        int   oi = __shfl_xor(i1, m, 64);
        if (ov > v1 || (ov == v1 && oi < i1)) { v1 = ov; i1 = oi; }
    }
    // ---- top-2: exclude i1, repeat ----
    float v2 = (e_my == i1) ? -3.402823466e+38f : mylg;
    int   i2 = e_my;
#pragma unroll
    for (int m = 1; m <= 4; m <<= 1) {
        float ov = __shfl_xor(v2, m, 64);
        int   oi = __shfl_xor(i2, m, 64);
        if (ov > v2 || (ov == v2 && oi < i2)) { v2 = ov; i2 = oi; }
    }

    // ---- softmax over the 2 selected logits (fp32, stable: v1 >= v2) ----
    const float ed  = expf(v2 - v1);
    const float inv = 1.0f / (1.0f + ed);

    const int tok = tok0 + t_loc;
    if (lane < 32 && e_my == 0 && tok < T) {
        *reinterpret_cast<float2*>(out_scores + 2 * tok) = make_float2(inv, ed * inv);
        *reinterpret_cast<float2*>(out_idx    + 2 * tok) = make_float2((float)i1, (float)i2);
        atomicAdd(&cnt[i1], 1);
        atomicAdd(&cnt[i2], 1);
    }

    __syncthreads();
    if (threadIdx.x < NEXP)
        atomicAdd(&hist[threadIdx.x], (float)cnt[threadIdx.x]);
}

extern "C" void kernel_launch(void* const* d_in, const int* in_sizes, int n_in,
                              void* d_out, int out_size, void* d_ws, size_t ws_size,
                              hipStream_t stream)
{
    const float* x = (const float*)d_in[0];
    const float* W = (const float*)d_in[1];
    const int T = in_sizes[0] / HDIM;          // 16384

    float* out        = (float*)d_out;
    float* out_scores = out;                   // [T,2]
    float* out_idx    = out + (size_t)2 * T;   // [T,2]
    float* hist       = out + (size_t)4 * T;   // [8]

    // zero the 8 hist slots every call (atomics accumulate into them)
    hipMemsetAsync(hist, 0, NEXP * sizeof(float), stream);

    const int nblocks = (T + TOK_PB - 1) / TOK_PB;   // 512
    router_main<<<nblocks, BLOCK, 0, stream>>>(x, W, out_scores, out_idx, hist, T);
}

// Round 8
// 44.271 us; speedup vs baseline: 1.1908x; 1.1908x over previous
//
#include <hip/hip_runtime.h>
#include <math.h>

#define HDIM 2048
#define NEXP 8
#define TB 4                          // tokens per wave
#define BLOCK 256
#define WAVES_PB 4
#define TOK_PB (WAVES_PB * TB)        // 16 tokens per block
#define CH 256                        // floats of H per chunk (1 KB/token/wave)
#define NCH (HDIM / CH)               // 8 chunks

typedef float f32x4 __attribute__((ext_vector_type(4)));

// ---------------------------------------------------------------------------
// R8: R1 geometry (best measured: TB=4, 256thr, 1024 blocks, W from global)
// + software-pipelined x prefetch. Theory: all rounds are bound by per-wave
// issue serialization — the W vmcnt wait in iter c blocks the x loads of
// iter c+1 (in-order issue), exposing full memory latency once per iter.
// Fix: explicit register double-buffer xc/xn; xn(c+1) issues BEFORE the W
// loads of iter c (compiler waitcnt for W leaves xn in flight). x uses
// nontemporal loads (read-once stream) so L1 stays W-hot.
// ---------------------------------------------------------------------------
__global__ __launch_bounds__(BLOCK) void
router_main(const float* __restrict__ x,
            const float* __restrict__ W,
            float* __restrict__ out_scores,   // [T,2]
            float* __restrict__ out_idx,      // [T,2] as float
            float* __restrict__ hist,         // [8], pre-zeroed
            int T)
{
    __shared__ int cnt[NEXP];
    if (threadIdx.x < NEXP) cnt[threadIdx.x] = 0;
    __syncthreads();

    const int lane = threadIdx.x & 63;
    const int wv   = threadIdx.x >> 6;
    const int tok0 = blockIdx.x * TOK_PB + wv * TB;

    const float* xb[TB];
#pragma unroll
    for (int t = 0; t < TB; ++t) {
        int tt = tok0 + t; if (tt > T - 1) tt = T - 1;
        xb[t] = x + (size_t)tt * HDIM + lane * 4;
    }
    const float* wb = W + lane * 4;

    float acc[TB * NEXP];
#pragma unroll
    for (int i = 0; i < TB * NEXP; ++i) acc[i] = 0.f;

    // ---- prolog: x chunk 0 into current regs (non-temporal stream) ----
    f32x4 xc[TB], xn[TB];
#pragma unroll
    for (int t = 0; t < TB; ++t)
        xc[t] = __builtin_nontemporal_load(reinterpret_cast<const f32x4*>(xb[t]));

#pragma unroll
    for (int c = 0; c < NCH; ++c) {
        const int h = c * CH;

        // (1) prefetch x chunk c+1 FIRST — stays in flight across the W wait
        if (c + 1 < NCH) {
#pragma unroll
            for (int t = 0; t < TB; ++t)
                xn[t] = __builtin_nontemporal_load(
                    reinterpret_cast<const f32x4*>(xb[t] + h + CH));
        }
        // keep xn loads older than W loads in the VMEM queue
        asm volatile("" ::: "memory");

        // (2) W chunk c (L1/L2-hot; compiler waits vmcnt(~4) for these,
        //     leaving the xn stream outstanding)
        f32x4 w[NEXP];
#pragma unroll
        for (int e = 0; e < NEXP; ++e)
            w[e] = *reinterpret_cast<const f32x4*>(wb + (size_t)e * HDIM + h);

        // (3) FMA on the ALREADY-RESIDENT xc — no x wait on this path
#pragma unroll
        for (int t = 0; t < TB; ++t) {
#pragma unroll
            for (int e = 0; e < NEXP; ++e) {
                float a = acc[t * NEXP + e];
                a = fmaf(xc[t].x, w[e].x, a);
                a = fmaf(xc[t].y, w[e].y, a);
                a = fmaf(xc[t].z, w[e].z, a);
                a = fmaf(xc[t].w, w[e].w, a);
                acc[t * NEXP + e] = a;
            }
        }

        // (4) rotate (full unroll -> pure register renaming, no v_movs)
        if (c + 1 < NCH) {
#pragma unroll
            for (int t = 0; t < TB; ++t) xc[t] = xn[t];
        }
    }

    // ---- reduce 32 partial sums across 64 lanes (R1-verified fold) ----
#pragma unroll
    for (int j = 0; j < 32; ++j) acc[j] += __shfl_xor(acc[j], 32, 64);

#define FOLD(SM)                                                          \
    {                                                                     \
        const bool up = (lane & SM) != 0;                                 \
        _Pragma("unroll")                                                 \
        for (int j = 0; j < SM; ++j) {                                    \
            float keep = up ? acc[j + SM] : acc[j];                       \
            float send = up ? acc[j] : acc[j + SM];                       \
            acc[j] = keep + __shfl_xor(send, SM, 64);                     \
        }                                                                 \
    }
    FOLD(16) FOLD(8) FOLD(4) FOLD(2) FOLD(1)
#undef FOLD

    // lane l holds logit(token tok0 + ((l&31)>>3), expert l&7)
    const int e_my  = lane & 7;
    const int t_loc = (lane & 31) >> 3;
    const float mylg = acc[0];

    // ---- top-1 within each aligned 8-lane group (tie -> lower index) ----
    float v1 = mylg;
    int   i1 = e_my;
#pragma unroll
    for (int m = 1; m <= 4; m <<= 1) {
        float ov = __shfl_xor(v1, m, 64);
        int   oi = __shfl_xor(i1, m, 64);
        if (ov > v1 || (ov == v1 && oi < i1)) { v1 = ov; i1 = oi; }
    }
    // ---- top-2: exclude i1, repeat ----
    float v2 = (e_my == i1) ? -3.402823466e+38f : mylg;
    int   i2 = e_my;
#pragma unroll
    for (int m = 1; m <= 4; m <<= 1) {
        float ov = __shfl_xor(v2, m, 64);
        int   oi = __shfl_xor(i2, m, 64);
        if (ov > v2 || (ov == v2 && oi < i2)) { v2 = ov; i2 = oi; }
    }

    // ---- softmax over the 2 selected logits (fp32, stable: v1 >= v2) ----
    const float ed  = expf(v2 - v1);
    const float inv = 1.0f / (1.0f + ed);

    const int tok = tok0 + t_loc;
    if (lane < 32 && e_my == 0 && tok < T) {
        *reinterpret_cast<float2*>(out_scores + 2 * tok) = make_float2(inv, ed * inv);
        *reinterpret_cast<float2*>(out_idx    + 2 * tok) = make_float2((float)i1, (float)i2);
        atomicAdd(&cnt[i1], 1);
        atomicAdd(&cnt[i2], 1);
    }

    __syncthreads();
    // integer-valued float adds (< 2^24) are exact -> order-independent,
    // deterministic across replays.
    if (threadIdx.x < NEXP)
        atomicAdd(&hist[threadIdx.x], (float)cnt[threadIdx.x]);
}

extern "C" void kernel_launch(void* const* d_in, const int* in_sizes, int n_in,
                              void* d_out, int out_size, void* d_ws, size_t ws_size,
                              hipStream_t stream)
{
    const float* x = (const float*)d_in[0];
    const float* W = (const float*)d_in[1];
    const int T = in_sizes[0] / HDIM;          // 16384

    float* out        = (float*)d_out;
    float* out_scores = out;                   // [T,2]
    float* out_idx    = out + (size_t)2 * T;   // [T,2]
    float* hist       = out + (size_t)4 * T;   // [8]

    // zero the 8 hist slots every call (atomics accumulate into them)
    hipMemsetAsync(hist, 0, NEXP * sizeof(float), stream);

    const int nblocks = (T + TOK_PB - 1) / TOK_PB;   // 1024
    router_main<<<nblocks, BLOCK, 0, stream>>>(x, W, out_scores, out_idx, hist, T);
}

// Round 9
// 41.554 us; speedup vs baseline: 1.2687x; 1.0654x over previous
//
#include <hip/hip_runtime.h>
#include <math.h>

#define HDIM 2048
#define NEXP 8
#define TB 4                          // tokens per wave
#define BLOCK 256
#define WAVES_PB 4
#define TOK_PB (WAVES_PB * TB)        // 16 tokens per block
#define CH 256                        // floats of H per chunk (1 KB/token/wave)
#define NCH (HDIM / CH)               // 8 chunks

typedef float f32x4 __attribute__((ext_vector_type(4)));

// ---------------------------------------------------------------------------
// R9: R1 geometry + correctly-ordered depth-2 x pipeline.
// VMEM queue drains oldest-first: to keep the x stream outstanding across
// the W-wait, x prefetch must be issued AFTER W (R8 had it inverted ->
// every W-wait was vmcnt(0) and drained the prefetch). Per iteration:
//   issue W_c (2 groups of 4)  ->  issue xpre_{c+2}  ->  FMA(xc, w)
// The compiler's wait for w[] is vmcnt(4), leaving the 4 newest x loads in
// flight; x gets ~2 iterations of lookahead (> HBM latency). Regular cached
// loads everywhere (x is 134 MB < 256 MB L3 -> partial residency across
// replays is free BW). Epilogue: R1-verified fold -> top-2 -> softmax ->
// stores; histogram via LDS counts + 8 float atomics/block (integer-valued
// float adds < 2^24 are exact -> deterministic).
// ---------------------------------------------------------------------------
__global__ __launch_bounds__(BLOCK) void
router_main(const float* __restrict__ x,
            const float* __restrict__ W,
            float* __restrict__ out_scores,   // [T,2]
            float* __restrict__ out_idx,      // [T,2] as float
            float* __restrict__ hist,         // [8], pre-zeroed
            int T)
{
    __shared__ int cnt[NEXP];
    if (threadIdx.x < NEXP) cnt[threadIdx.x] = 0;
    __syncthreads();

    const int lane = threadIdx.x & 63;
    const int wv   = threadIdx.x >> 6;
    const int tok0 = blockIdx.x * TOK_PB + wv * TB;

    const float* xb[TB];
#pragma unroll
    for (int t = 0; t < TB; ++t) {
        int tt = tok0 + t; if (tt > T - 1) tt = T - 1;
        xb[t] = x + (size_t)tt * HDIM + lane * 4;
    }
    const float* wb = W + lane * 4;

    float acc[TB * NEXP];
#pragma unroll
    for (int i = 0; i < TB * NEXP; ++i) acc[i] = 0.f;

    // ---- prolog: x chunks 0 and 1 in flight / resident ----
    f32x4 xc[TB], xp1[TB], xp2[TB];
#pragma unroll
    for (int t = 0; t < TB; ++t)
        xc[t] = *reinterpret_cast<const f32x4*>(xb[t]);
#pragma unroll
    for (int t = 0; t < TB; ++t)
        xp1[t] = *reinterpret_cast<const f32x4*>(xb[t] + CH);

#pragma unroll
    for (int c = 0; c < NCH; ++c) {
        const int h = c * CH;

        // (1) W chunk c — two 4-expert groups (keeps live W regs at 16)
        f32x4 w[NEXP];
#pragma unroll
        for (int e = 0; e < NEXP; ++e)
            w[e] = *reinterpret_cast<const f32x4*>(wb + (size_t)e * HDIM + h);

        // order fence: W loads sit deeper in the VMEM queue than xpre below
        asm volatile("" ::: "memory");

        // (2) x prefetch chunk c+2 — NEWEST in queue; the compiler's
        //     vmcnt wait for w[] leaves exactly these outstanding
        if (c + 2 < NCH) {
#pragma unroll
            for (int t = 0; t < TB; ++t)
                xp2[t] = *reinterpret_cast<const f32x4*>(xb[t] + h + 2 * CH);
        }
        asm volatile("" ::: "memory");

        // (3) FMA on resident xc against w (wait drains W, not xpre)
#pragma unroll
        for (int t = 0; t < TB; ++t) {
#pragma unroll
            for (int e = 0; e < NEXP; ++e) {
                float a = acc[t * NEXP + e];
                a = fmaf(xc[t].x, w[e].x, a);
                a = fmaf(xc[t].y, w[e].y, a);
                a = fmaf(xc[t].z, w[e].z, a);
                a = fmaf(xc[t].w, w[e].w, a);
                acc[t * NEXP + e] = a;
            }
        }

        // (4) rotate pipeline (full unroll -> register renaming)
#pragma unroll
        for (int t = 0; t < TB; ++t) { xc[t] = xp1[t]; xp1[t] = xp2[t]; }
    }

    // ---- reduce 32 partial sums across 64 lanes (R1-verified fold) ----
#pragma unroll
    for (int j = 0; j < 32; ++j) acc[j] += __shfl_xor(acc[j], 32, 64);

#define FOLD(SM)                                                          \
    {                                                                     \
        const bool up = (lane & SM) != 0;                                 \
        _Pragma("unroll")                                                 \
        for (int j = 0; j < SM; ++j) {                                    \
            float keep = up ? acc[j + SM] : acc[j];                       \
            float send = up ? acc[j] : acc[j + SM];                       \
            acc[j] = keep + __shfl_xor(send, SM, 64);                     \
        }                                                                 \
    }
    FOLD(16) FOLD(8) FOLD(4) FOLD(2) FOLD(1)
#undef FOLD

    // lane l holds logit(token tok0 + ((l&31)>>3), expert l&7)
    const int e_my  = lane & 7;
    const int t_loc = (lane & 31) >> 3;
    const float mylg = acc[0];

    // ---- top-1 within each aligned 8-lane group (tie -> lower index) ----
    float v1 = mylg;
    int   i1 = e_my;
#pragma unroll
    for (int m = 1; m <= 4; m <<= 1) {
        float ov = __shfl_xor(v1, m, 64);
        int   oi = __shfl_xor(i1, m, 64);
        if (ov > v1 || (ov == v1 && oi < i1)) { v1 = ov; i1 = oi; }
    }
    // ---- top-2: exclude i1, repeat ----
    float v2 = (e_my == i1) ? -3.402823466e+38f : mylg;
    int   i2 = e_my;
#pragma unroll
    for (int m = 1; m <= 4; m <<= 1) {
        float ov = __shfl_xor(v2, m, 64);
        int   oi = __shfl_xor(i2, m, 64);
        if (ov > v2 || (ov == v2 && oi < i2)) { v2 = ov; i2 = oi; }
    }

    // ---- softmax over the 2 selected logits (fp32, stable: v1 >= v2) ----
    const float ed  = expf(v2 - v1);
    const float inv = 1.0f / (1.0f + ed);

    const int tok = tok0 + t_loc;
    if (lane < 32 && e_my == 0 && tok < T) {
        *reinterpret_cast<float2*>(out_scores + 2 * tok) = make_float2(inv, ed * inv);
        *reinterpret_cast<float2*>(out_idx    + 2 * tok) = make_float2((float)i1, (float)i2);
        atomicAdd(&cnt[i1], 1);
        atomicAdd(&cnt[i2], 1);
    }

    __syncthreads();
    // integer-valued float adds (< 2^24) are exact -> order-independent,
    // deterministic across replays.
    if (threadIdx.x < NEXP)
        atomicAdd(&hist[threadIdx.x], (float)cnt[threadIdx.x]);
}

extern "C" void kernel_launch(void* const* d_in, const int* in_sizes, int n_in,
                              void* d_out, int out_size, void* d_ws, size_t ws_size,
                              hipStream_t stream)
{
    const float* x = (const float*)d_in[0];
    const float* W = (const float*)d_in[1];
    const int T = in_sizes[0] / HDIM;          // 16384

    float* out        = (float*)d_out;
    float* out_scores = out;                   // [T,2]
    float* out_idx    = out + (size_t)2 * T;   // [T,2]
    float* hist       = out + (size_t)4 * T;   // [8]

    // zero the 8 hist slots every call (atomics accumulate into them)
    hipMemsetAsync(hist, 0, NEXP * sizeof(float), stream);

    const int nblocks = (T + TOK_PB - 1) / TOK_PB;   // 1024
    router_main<<<nblocks, BLOCK, 0, stream>>>(x, W, out_scores, out_idx, hist, T);
}